// Round 1
// baseline (16.249 us; speedup 1.0000x reference)
//
#include <hip/hip_runtime.h>
#include <hip/hip_bf16.h>

// Problem constants (from reference): B=16, M_ROWS=128, S=2048, D=1024, pct=0.2
constexpr int BATCH = 16;
constexpr int MROWS = 128;
constexpr int SEQ   = 2048;
constexpr int DIM   = 1024;

// One block (256 threads) per (b, m) row.
// Phase 1: scan the mask row to find first/last nonzero index.
// Phase 2: mean of reps[b, ns..ne, :] -> out[b, m, :].
__global__ __launch_bounds__(256) void numreps_kernel(
    const float* __restrict__ mask,   // [B, M, S]
    const float* __restrict__ reps,   // [B, S, D]
    float* __restrict__ out)          // [B, M, D]
{
    const int row = blockIdx.x;           // 0 .. B*M-1
    const int b   = row / MROWS;
    const int tid = threadIdx.x;          // 0..255

    const float* mrow = mask + (size_t)row * SEQ;

    // ---- Phase 1: find first/last index with mask > 0 (values are 0.0/1.0)
    int localFirst = SEQ;   // big
    int localLast  = -1;
    // SEQ/4 = 512 float4s, 256 threads -> 2 iterations each
    const float4* m4 = reinterpret_cast<const float4*>(mrow);
    #pragma unroll
    for (int it = 0; it < SEQ / 4 / 256; ++it) {
        const int i = tid + it * 256;
        float4 v = m4[i];
        const int base = i * 4;
        if (v.x > 0.f) { localFirst = min(localFirst, base + 0); localLast = max(localLast, base + 0); }
        if (v.y > 0.f) { localFirst = min(localFirst, base + 1); localLast = max(localLast, base + 1); }
        if (v.z > 0.f) { localFirst = min(localFirst, base + 2); localLast = max(localLast, base + 2); }
        if (v.w > 0.f) { localFirst = min(localFirst, base + 3); localLast = max(localLast, base + 3); }
    }

    __shared__ int sFirst[256];
    __shared__ int sLast[256];
    sFirst[tid] = localFirst;
    sLast[tid]  = localLast;
    __syncthreads();
    #pragma unroll
    for (int off = 128; off > 0; off >>= 1) {
        if (tid < off) {
            sFirst[tid] = min(sFirst[tid], sFirst[tid + off]);
            sLast[tid]  = max(sLast[tid],  sLast[tid + off]);
        }
        __syncthreads();
    }
    const int first = sFirst[0];
    const int last  = sLast[0];

    float4* outp = reinterpret_cast<float4*>(out + (size_t)row * DIM) + tid; // DIM/4 == 256

    if (last < 0) {
        // no ones in this row: norm_mask == 0 -> output zeros
        float4 z; z.x = 0.f; z.y = 0.f; z.z = 0.f; z.w = 0.f;
        *outp = z;
        return;
    }

    // ---- expand_window, replicating float32 truncation semantics
    const int wlen   = last - first + 1;
    const int expand = (int)((float)wlen * 0.2f);   // torch .int() / jnp astype(int32) truncates
    const int ns = max(first - expand, 0);
    const int ne = min(last + expand, SEQ - 1);
    const int L  = ne - ns + 1;                     // num_ones >= 1, clamp is a no-op
    const float inv = 1.0f / (float)L;

    // ---- Phase 2: windowed mean over reps rows (each row 4 KB, coalesced)
    const float* rbase = reps + ((size_t)b * SEQ + (size_t)ns) * DIM + (size_t)tid * 4;
    float ax = 0.f, ay = 0.f, az = 0.f, aw = 0.f;
    for (int s = 0; s < L; ++s) {
        float4 v = *reinterpret_cast<const float4*>(rbase + (size_t)s * DIM);
        ax += v.x; ay += v.y; az += v.z; aw += v.w;
    }
    float4 o; o.x = ax * inv; o.y = ay * inv; o.z = az * inv; o.w = aw * inv;
    *outp = o;
}

extern "C" void kernel_launch(void* const* d_in, const int* in_sizes, int n_in,
                              void* d_out, int out_size, void* d_ws, size_t ws_size,
                              hipStream_t stream) {
    const float* mask = (const float*)d_in[0];  // number_mask [16,128,2048] f32
    const float* reps = (const float*)d_in[1];  // reps [16,2048,1024] f32
    float* out = (float*)d_out;                 // [16,128,1024] f32

    dim3 grid(BATCH * MROWS);
    dim3 block(256);
    numreps_kernel<<<grid, block, 0, stream>>>(mask, reps, out);
}